// Round 1
// baseline (162.377 us; speedup 1.0000x reference)
//
#include <hip/hip_runtime.h>

// out[i] = prod_j sigmoid((ub[j] - logit(bc[idx[i][j]])) / (ub[j] - lb[j] + 1e-4))
// Memory-bound: 96 MiB index read + 32 MiB output write ~= 20.4 us @ 6.3 TB/s.
// Strategy: per-block 3x1000 sigmoid LUT in LDS (transcendentals are O(bins),
// not O(rows)); hot loop = 3x int4 coalesced loads -> 12 LDS gathers -> float4 store.

#define EPS 1e-4f

__global__ __launch_bounds__(256) void pm_kernel(
    const float* __restrict__ bc,      // [nbins]
    const int*   __restrict__ idx,     // [ndiffs, 3] int32
    const float* __restrict__ lo,      // [3]
    const float* __restrict__ hi,      // [3]
    float*       __restrict__ out,     // [ndiffs]
    int nbins, int ndiffs)
{
    __shared__ float tab[3][1024];   // 12 KB; nbins <= 1024 (actual 1000)

    // Effective bounds (reference swaps if lb > ub)
    const float lb0 = fminf(lo[0], hi[0]), ub0 = fmaxf(lo[0], hi[0]);
    const float lb1 = fminf(lo[1], hi[1]), ub1 = fmaxf(lo[1], hi[1]);
    const float lb2 = fminf(lo[2], hi[2]), ub2 = fmaxf(lo[2], hi[2]);
    const float r0 = 1.0f / (ub0 - lb0 + EPS);
    const float r1 = 1.0f / (ub1 - lb1 + EPS);
    const float r2 = 1.0f / (ub2 - lb2 + EPS);

    // Build the per-(bound, bin) sigmoid table: ~4 strips of 256 threads.
    for (int b = threadIdx.x; b < nbins; b += blockDim.x) {
        const float t = bc[b];
        const float g = __logf(t / (1.0f - t));          // logit
        tab[0][b] = 1.0f / (1.0f + __expf(-(ub0 - g) * r0));
        tab[1][b] = 1.0f / (1.0f + __expf(-(ub1 - g) * r1));
        tab[2][b] = 1.0f / (1.0f + __expf(-(ub2 - g) * r2));
    }
    __syncthreads();

    const int tid    = blockIdx.x * blockDim.x + threadIdx.x;
    const int stride = gridDim.x * blockDim.x;
    const int nvec   = ndiffs >> 2;                      // 4 rows per thread

    const int4* __restrict__ idx4 = (const int4*)idx;    // 12 ints = 3x int4 per group
    float4*     __restrict__ out4 = (float4*)out;

    for (int v = tid; v < nvec; v += stride) {
        const int4 a = idx4[3 * v + 0];
        const int4 b = idx4[3 * v + 1];
        const int4 c = idx4[3 * v + 2];
        float4 r;
        r.x = tab[0][a.x] * tab[1][a.y] * tab[2][a.z];
        r.y = tab[0][a.w] * tab[1][b.x] * tab[2][b.y];
        r.z = tab[0][b.z] * tab[1][b.w] * tab[2][c.x];
        r.w = tab[0][c.y] * tab[1][c.z] * tab[2][c.w];
        out4[v] = r;
    }

    // Tail (ndiffs % 4) — none for 8388608, but keep it general.
    for (int i = (nvec << 2) + tid; i < ndiffs; i += stride) {
        const int i0 = idx[3 * i + 0];
        const int i1 = idx[3 * i + 1];
        const int i2 = idx[3 * i + 2];
        out[i] = tab[0][i0] * tab[1][i1] * tab[2][i2];
    }
}

extern "C" void kernel_launch(void* const* d_in, const int* in_sizes, int n_in,
                              void* d_out, int out_size, void* d_ws, size_t ws_size,
                              hipStream_t stream)
{
    const float* bc  = (const float*)d_in[0];   // bin_centers [nbins]
    const int*   idx = (const int*)  d_in[1];   // observation_probability_index [ndiffs*3]
    const float* lo  = (const float*)d_in[2];   // lower_bounds [3]
    const float* hi  = (const float*)d_in[3];   // upper_bounds [3]
    float*       out = (float*)d_out;

    const int nbins  = in_sizes[0];
    const int ndiffs = out_size;

    const int nvec   = ndiffs >> 2;
    int blocks = (nvec + 255) / 256;             // one float4-group per thread
    if (blocks < 1) blocks = 1;

    pm_kernel<<<blocks, 256, 0, stream>>>(bc, idx, lo, hi, out, nbins, ndiffs);
}